// Round 2
// baseline (600.383 us; speedup 1.0000x reference)
//
#include <hip/hip_runtime.h>
#include <cstddef>

#define C_    128
#define DW_   256
#define HW_   (192 * 192)
#define B_    8
#define NPIX_ (B_ * HW_)
#define EPS_  1e-6f
#define PA_   136            // padded A-tile row stride in bf16 elems (272 B)

typedef __bf16 bf16_t;
typedef __bf16 bf16x8 __attribute__((ext_vector_type(8)));
typedef __bf16 bf16x4 __attribute__((ext_vector_type(4)));
typedef float  f32x4  __attribute__((ext_vector_type(4)));

__device__ __forceinline__ float4 ld4(const float* p) { return *(const float4*)p; }

// ---------------------------------------------------------------------------
// Prep: fold depthwise affine into w1/b1; cast weights to bf16 in B-fragment
// order: flat[((t*4+s)*64+lane)*8 + j] = W[k][n], n = t*16+(lane&15),
// k = s*32 + (lane>>4)*8 + j.  (A/B fragment k-decomposition of 16x16x32.)
// ---------------------------------------------------------------------------
__global__ void k_prep(const float* __restrict__ w1, const float* __restrict__ b1,
                       const float* __restrict__ wdw, const float* __restrict__ bdw,
                       const float* __restrict__ w2, const float* __restrict__ wf1,
                       const float* __restrict__ wf2,
                       bf16_t* __restrict__ wt1, bf16_t* __restrict__ wt2,
                       bf16_t* __restrict__ wtf1, bf16_t* __restrict__ wtf2,
                       float* __restrict__ b1f)
{
    const int id = blockIdx.x * blockDim.x + threadIdx.x;
    const int stride = gridDim.x * blockDim.x;
    for (int n = id; n < DW_; n += stride)
        b1f[n] = b1[n] * wdw[n] + bdw[n];
    for (int f = id; f < 32768; f += stride) {          // w1 (fold wdw), N=256
        const int j = f & 7, lane = (f >> 3) & 63, s = (f >> 9) & 3, t = f >> 11;
        const int n = t * 16 + (lane & 15);
        const int k = s * 32 + ((lane >> 4) << 3) + j;
        wt1[f] = (bf16_t)(w1[k * DW_ + n] * wdw[n]);
    }
    for (int f = id; f < 16384; f += stride) {          // w2, N=128
        const int j = f & 7, lane = (f >> 3) & 63, s = (f >> 9) & 3, t = f >> 11;
        const int n = t * 16 + (lane & 15);
        const int k = s * 32 + ((lane >> 4) << 3) + j;
        wt2[f] = (bf16_t)(w2[k * C_ + n]);
    }
    for (int f = id; f < 32768; f += stride) {          // wf1, N=256
        const int j = f & 7, lane = (f >> 3) & 63, s = (f >> 9) & 3, t = f >> 11;
        const int n = t * 16 + (lane & 15);
        const int k = s * 32 + ((lane >> 4) << 3) + j;
        wtf1[f] = (bf16_t)(wf1[k * DW_ + n]);
    }
    for (int f = id; f < 16384; f += stride) {          // wf2, N=128
        const int j = f & 7, lane = (f >> 3) & 63, s = (f >> 9) & 3, t = f >> 11;
        const int n = t * 16 + (lane & 15);
        const int k = s * 32 + ((lane >> 4) << 3) + j;
        wtf2[f] = (bf16_t)(wf2[k * C_ + n]);
    }
}

// ---------------------------------------------------------------------------
// Phase 1: LN1 -> (w1*wdw) MFMA -> gate -> sg (fp32 to d_out) + gap partials.
// 64 pixels/block, 4 waves x 16 pixels.  One atomic/channel/block at kernel
// end (fire-and-forget; nothing waits on it).
// ---------------------------------------------------------------------------
__global__ __launch_bounds__(256) void k_phase1(
    const float* __restrict__ x,
    const float* __restrict__ ln1s, const float* __restrict__ ln1b,
    const bf16_t* __restrict__ wt1, const float* __restrict__ b1f,
    float* __restrict__ sg_out, float* __restrict__ gap)
{
    __shared__ __align__(16) bf16_t sA[64 * PA_];
    __shared__ float sRed[4 * C_];           // per-wave gap partials (2 KB)
    const int tid = threadIdx.x;
    const int pix0 = blockIdx.x * 64;
    const int batch = pix0 / HW_;

    // ---- LN1: 4 threads per pixel, 32 ch each ----
    {
        const int p = tid >> 2, sub = tid & 3;
        const float* xr = x + (size_t)(pix0 + p) * C_ + sub * 32;
        float4 v[8];
        float s = 0.f, ss = 0.f;
        #pragma unroll
        for (int u = 0; u < 8; u++) {
            v[u] = ld4(xr + u * 4);
            s  += v[u].x + v[u].y + v[u].z + v[u].w;
            ss += v[u].x * v[u].x + v[u].y * v[u].y + v[u].z * v[u].z + v[u].w * v[u].w;
        }
        s += __shfl_xor(s, 1); ss += __shfl_xor(ss, 1);
        s += __shfl_xor(s, 2); ss += __shfl_xor(ss, 2);
        const float mu  = s * (1.f / C_);
        const float var = ss * (1.f / C_) - mu * mu;
        const float rr  = rsqrtf(var + EPS_);
        #pragma unroll
        for (int u = 0; u < 8; u++) {
            const int c0 = sub * 32 + u * 4;
            const float4 sc = ld4(ln1s + c0), bi = ld4(ln1b + c0);
            bf16x4 o;
            o[0] = (bf16_t)((v[u].x - mu) * rr * sc.x + bi.x);
            o[1] = (bf16_t)((v[u].y - mu) * rr * sc.y + bi.y);
            o[2] = (bf16_t)((v[u].z - mu) * rr * sc.z + bi.z);
            o[3] = (bf16_t)((v[u].w - mu) * rr * sc.w + bi.w);
            *(bf16x4*)(&sA[p * PA_ + c0]) = o;
        }
    }
    __syncthreads();

    const int lane = tid & 63, wave = tid >> 6;
    const int l15 = lane & 15, quad = lane >> 4;

    bf16x8 af[4];
    #pragma unroll
    for (int s = 0; s < 4; s++)
        af[s] = *(const bf16x8*)(&sA[(wave * 16 + l15) * PA_ + s * 32 + quad * 8]);

    float gacc[8];
    #pragma unroll
    for (int t = 0; t < 8; t++) {
        f32x4 a0 = {0.f, 0.f, 0.f, 0.f};
        f32x4 a1 = {0.f, 0.f, 0.f, 0.f};
        #pragma unroll
        for (int s = 0; s < 4; s++) {
            const bf16x8 b0 = *(const bf16x8*)(wt1 + ((size_t)((t    ) * 4 + s) * 64 + lane) * 8);
            const bf16x8 b1 = *(const bf16x8*)(wt1 + ((size_t)((t + 8) * 4 + s) * 64 + lane) * 8);
            a0 = __builtin_amdgcn_mfma_f32_16x16x32_bf16(af[s], b0, a0, 0, 0, 0);
            a1 = __builtin_amdgcn_mfma_f32_16x16x32_bf16(af[s], b1, a1, 0, 0, 0);
        }
        const float bb0 = b1f[t * 16 + l15], bb1 = b1f[128 + t * 16 + l15];
        float gs = 0.f;
        #pragma unroll
        for (int r = 0; r < 4; r++) {
            const float g = (a0[r] + bb0) * (a1[r] + bb1);
            const int p = pix0 + wave * 16 + quad * 4 + r;
            sg_out[(size_t)p * C_ + t * 16 + l15] = g;
            gs += g;
        }
        gacc[t] = gs;           // stays in registers; NO atomic in the loop
    }

    // ---- gap reduction: butterfly over quads, LDS over waves, 1 atomic/ch ----
    #pragma unroll
    for (int t = 0; t < 8; t++) {
        float g = gacc[t];
        g += __shfl_xor(g, 16);
        g += __shfl_xor(g, 32);
        if (lane < 16) sRed[wave * C_ + t * 16 + lane] = g;
    }
    __syncthreads();
    if (tid < C_) {
        const float s4 = sRed[tid] + sRed[C_ + tid] + sRed[2 * C_ + tid] + sRed[3 * C_ + tid];
        atomicAdd(&gap[batch * C_ + tid], s4);
    }
}

// ---------------------------------------------------------------------------
// SE dense: att[b][d] = (gap[b]/HW) . wse[:,d] + bse[d]
// ---------------------------------------------------------------------------
__global__ __launch_bounds__(128) void k_se(
    const float* __restrict__ gap, const float* __restrict__ wse,
    const float* __restrict__ bse, float* __restrict__ att)
{
    const int b = blockIdx.x;
    const int d = threadIdx.x;
    float acc = bse[d];
    const float inv = 1.0f / (float)HW_;
    for (int cc = 0; cc < C_; cc++)
        acc = fmaf(gap[b * C_ + cc] * inv, wse[cc * C_ + d], acc);
    att[b * C_ + d] = acc;
}

// ---------------------------------------------------------------------------
// Phase 2: sm=sg*att -> w2 MFMA -> y -> LN2 (in-register) -> wf1 MFMA + gate
// -> wf2 MFMA -> out.  64 pixels/block.
// LN2 needs NO LDS re-partition: after the w2 MFMA each pixel's 128 channels
// live within one 16-lane quad-group (n = t*16+l15), so mean/var = in-thread
// sum over t + __shfl_xor(1,2,4,8).  ybuf is gone; two 17.4 KB bf16 A-tile
// buffers ping-pong (sm->A, cn->B, cg->A).  LDS 51200 -> 34816 B, barriers
// 4 -> 3, occupancy cap 3 -> 4 blocks/CU (VGPR-capped).
// ---------------------------------------------------------------------------
__global__ __launch_bounds__(256) void k_phase2(
    const float* __restrict__ x, const float* __restrict__ att,
    const bf16_t* __restrict__ wt2, const float* __restrict__ b2,
    const float* __restrict__ ln2s, const float* __restrict__ ln2b,
    const bf16_t* __restrict__ wtf1, const float* __restrict__ bf1,
    const bf16_t* __restrict__ wtf2, const float* __restrict__ bf2,
    const float* __restrict__ beta, const float* __restrict__ gamma,
    float* __restrict__ io)
{
    __shared__ __align__(16) bf16_t sA[64 * PA_];          // sm, then cg
    __shared__ __align__(16) bf16_t sB[64 * PA_];          // cn

    const int tid = threadIdx.x;
    const int pix0 = blockIdx.x * 64;
    const int batch = pix0 / HW_;

    // ---- sm = sg * att -> sA (bf16) ----
    {
        const int p = tid >> 2, sub = tid & 3;
        const float* gr = io + (size_t)(pix0 + p) * C_ + sub * 32;
        const float* ar = att + batch * C_ + sub * 32;
        #pragma unroll
        for (int u = 0; u < 8; u++) {
            const float4 g = ld4(gr + u * 4), a = ld4(ar + u * 4);
            bf16x4 o;
            o[0] = (bf16_t)(g.x * a.x);
            o[1] = (bf16_t)(g.y * a.y);
            o[2] = (bf16_t)(g.z * a.z);
            o[3] = (bf16_t)(g.w * a.w);
            *(bf16x4*)(&sA[p * PA_ + sub * 32 + u * 4]) = o;
        }
    }
    __syncthreads();                                   // (1) sm ready

    const int lane = tid & 63, wave = tid >> 6;
    const int l15 = lane & 15, quad = lane >> 4;
    float yreg[32];
    float psum[4] = {0.f, 0.f, 0.f, 0.f};
    float psqr[4] = {0.f, 0.f, 0.f, 0.f};

    // ---- w2 GEMM + residual -> yreg, accumulate LN2 stats ----
    {
        bf16x8 af[4];
        #pragma unroll
        for (int s = 0; s < 4; s++)
            af[s] = *(const bf16x8*)(&sA[(wave * 16 + l15) * PA_ + s * 32 + quad * 8]);
        #pragma unroll
        for (int t = 0; t < 8; t++) {
            f32x4 acc = {0.f, 0.f, 0.f, 0.f};
            #pragma unroll
            for (int s = 0; s < 4; s++) {
                const bf16x8 b = *(const bf16x8*)(wt2 + ((size_t)(t * 4 + s) * 64 + lane) * 8);
                acc = __builtin_amdgcn_mfma_f32_16x16x32_bf16(af[s], b, acc, 0, 0, 0);
            }
            const int n = t * 16 + l15;
            const float b2n = b2[n], bta = beta[n];
            #pragma unroll
            for (int r = 0; r < 4; r++) {
                const int m = wave * 16 + quad * 4 + r;
                const float xv = x[(size_t)(pix0 + m) * C_ + n];
                const float yv = xv + bta * (acc[r] + b2n);
                yreg[t * 4 + r] = yv;
                psum[r] += yv;
                psqr[r] += yv * yv;
            }
        }
    }

    // ---- LN2 stats: quad-group butterfly (channels of pixel r live in the
    //      16 lanes sharing this quad) ----
    float mu[4], rr[4];
    #pragma unroll
    for (int r = 0; r < 4; r++) {
        float s1 = psum[r], s2 = psqr[r];
        s1 += __shfl_xor(s1, 1); s2 += __shfl_xor(s2, 1);
        s1 += __shfl_xor(s1, 2); s2 += __shfl_xor(s2, 2);
        s1 += __shfl_xor(s1, 4); s2 += __shfl_xor(s2, 4);
        s1 += __shfl_xor(s1, 8); s2 += __shfl_xor(s2, 8);
        mu[r] = s1 * (1.f / C_);
        const float var = s2 * (1.f / C_) - mu[r] * mu[r];
        rr[r] = rsqrtf(var + EPS_);
    }

    // ---- cn = LN2(y) -> sB (bf16, scalar b16 writes) ----
    #pragma unroll
    for (int t = 0; t < 8; t++) {
        const int n = t * 16 + l15;
        const float sc = ln2s[n], bi = ln2b[n];
        #pragma unroll
        for (int r = 0; r < 4; r++) {
            const int m = wave * 16 + quad * 4 + r;
            sB[m * PA_ + n] = (bf16_t)((yreg[t * 4 + r] - mu[r]) * rr[r] * sc + bi);
        }
    }
    __syncthreads();                                   // (2) cn ready; sA-reads done

    // ---- wf1 GEMM + gate -> sA (bf16) ----
    {
        bf16x8 af[4];
        #pragma unroll
        for (int s = 0; s < 4; s++)
            af[s] = *(const bf16x8*)(&sB[(wave * 16 + l15) * PA_ + s * 32 + quad * 8]);
        #pragma unroll
        for (int t = 0; t < 8; t++) {
            f32x4 a0 = {0.f, 0.f, 0.f, 0.f};
            f32x4 a1 = {0.f, 0.f, 0.f, 0.f};
            #pragma unroll
            for (int s = 0; s < 4; s++) {
                const bf16x8 b0 = *(const bf16x8*)(wtf1 + ((size_t)((t    ) * 4 + s) * 64 + lane) * 8);
                const bf16x8 b1 = *(const bf16x8*)(wtf1 + ((size_t)((t + 8) * 4 + s) * 64 + lane) * 8);
                a0 = __builtin_amdgcn_mfma_f32_16x16x32_bf16(af[s], b0, a0, 0, 0, 0);
                a1 = __builtin_amdgcn_mfma_f32_16x16x32_bf16(af[s], b1, a1, 0, 0, 0);
            }
            const float f1a = bf1[t * 16 + l15], f1b = bf1[128 + t * 16 + l15];
            #pragma unroll
            for (int r = 0; r < 4; r++) {
                const float cg = (a0[r] + f1a) * (a1[r] + f1b);
                sA[(wave * 16 + quad * 4 + r) * PA_ + t * 16 + l15] = (bf16_t)cg;
            }
        }
    }
    __syncthreads();                                   // (3) cg ready

    // ---- wf2 GEMM + final residual -> io ----
    {
        bf16x8 af[4];
        #pragma unroll
        for (int s = 0; s < 4; s++)
            af[s] = *(const bf16x8*)(&sA[(wave * 16 + l15) * PA_ + s * 32 + quad * 8]);
        #pragma unroll
        for (int t = 0; t < 8; t++) {
            f32x4 acc = {0.f, 0.f, 0.f, 0.f};
            #pragma unroll
            for (int s = 0; s < 4; s++) {
                const bf16x8 b = *(const bf16x8*)(wtf2 + ((size_t)(t * 4 + s) * 64 + lane) * 8);
                acc = __builtin_amdgcn_mfma_f32_16x16x32_bf16(af[s], b, acc, 0, 0, 0);
            }
            const int n = t * 16 + l15;
            const float fb = bf2[n], gm = gamma[n];
            #pragma unroll
            for (int r = 0; r < 4; r++) {
                const int m = wave * 16 + quad * 4 + r;
                io[(size_t)(pix0 + m) * C_ + n] = yreg[t * 4 + r] + gm * (acc[r] + fb);
            }
        }
    }
}

extern "C" void kernel_launch(void* const* d_in, const int* in_sizes, int n_in,
                              void* d_out, int out_size, void* d_ws, size_t ws_size,
                              hipStream_t stream)
{
    const float* x     = (const float*)d_in[0];
    const float* ln1s  = (const float*)d_in[1];
    const float* ln1b  = (const float*)d_in[2];
    const float* w1    = (const float*)d_in[3];
    const float* b1    = (const float*)d_in[4];
    const float* wdw   = (const float*)d_in[5];
    const float* bdw   = (const float*)d_in[6];
    const float* wse   = (const float*)d_in[7];
    const float* bse   = (const float*)d_in[8];
    const float* w2    = (const float*)d_in[9];
    const float* b2    = (const float*)d_in[10];
    const float* ln2s  = (const float*)d_in[11];
    const float* ln2b  = (const float*)d_in[12];
    const float* wf1   = (const float*)d_in[13];
    const float* bf1   = (const float*)d_in[14];
    const float* wf2   = (const float*)d_in[15];
    const float* bf2   = (const float*)d_in[16];
    const float* beta  = (const float*)d_in[17];
    const float* gamma = (const float*)d_in[18];

    float* out = (float*)d_out;
    char*  ws  = (char*)d_ws;
    float*  gap  = (float*)(ws);                 // 1024 f = 4 KB
    float*  attb = (float*)(ws + 4096);          // 1024 f = 4 KB
    float*  b1f  = (float*)(ws + 8192);          // 256 f  = 1 KB
    bf16_t* wt1  = (bf16_t*)(ws + 12288);        // 64 KB
    bf16_t* wt2  = (bf16_t*)(ws + 77824);        // 32 KB
    bf16_t* wtf1 = (bf16_t*)(ws + 110592);       // 64 KB
    bf16_t* wtf2 = (bf16_t*)(ws + 176128);       // 32 KB

    k_prep<<<192, 256, 0, stream>>>(w1, b1, wdw, bdw, w2, wf1, wf2,
                                    wt1, wt2, wtf1, wtf2, b1f);
    hipMemsetAsync(gap, 0, B_ * C_ * sizeof(float), stream);
    k_phase1<<<NPIX_ / 64, 256, 0, stream>>>(x, ln1s, ln1b, wt1, b1f, out, gap);
    k_se<<<B_, C_, 0, stream>>>(gap, wse, bse, attb);
    k_phase2<<<NPIX_ / 64, 256, 0, stream>>>(x, attb, wt2, b2, ln2s, ln2b,
                                             wtf1, bf1, wtf2, bf2, beta, gamma, out);
}

// Round 3
// 511.029 us; speedup vs baseline: 1.1749x; 1.1749x over previous
//
#include <hip/hip_runtime.h>
#include <cstddef>

#define C_    128
#define DW_   256
#define HW_   (192 * 192)
#define B_    8
#define NPIX_ (B_ * HW_)
#define EPS_  1e-6f
#define PA_   136            // padded A-tile row stride in bf16 elems (272 B)

typedef __bf16 bf16_t;
typedef __bf16 bf16x8 __attribute__((ext_vector_type(8)));
typedef __bf16 bf16x4 __attribute__((ext_vector_type(4)));
typedef float  f32x4  __attribute__((ext_vector_type(4)));

__device__ __forceinline__ float4 ld4(const float* p) { return *(const float4*)p; }

// ---------------------------------------------------------------------------
// Prep: zero gap; fold depthwise affine into w1/b1; cast weights to bf16 in
// B-fragment order: flat[((t*4+s)*64+lane)*8 + j] = W[k][n], n = t*16+(lane&15),
// k = s*32 + (lane>>4)*8 + j.  (A/B fragment k-decomposition of 16x16x32.)
// ---------------------------------------------------------------------------
__global__ void k_prep(const float* __restrict__ w1, const float* __restrict__ b1,
                       const float* __restrict__ wdw, const float* __restrict__ bdw,
                       const float* __restrict__ w2, const float* __restrict__ wf1,
                       const float* __restrict__ wf2,
                       bf16_t* __restrict__ wt1, bf16_t* __restrict__ wt2,
                       bf16_t* __restrict__ wtf1, bf16_t* __restrict__ wtf2,
                       float* __restrict__ b1f, float* __restrict__ gap)
{
    const int id = blockIdx.x * blockDim.x + threadIdx.x;
    const int stride = gridDim.x * blockDim.x;
    for (int n = id; n < B_ * C_; n += stride)
        gap[n] = 0.f;                                   // replaces hipMemsetAsync
    for (int n = id; n < DW_; n += stride)
        b1f[n] = b1[n] * wdw[n] + bdw[n];
    for (int f = id; f < 32768; f += stride) {          // w1 (fold wdw), N=256
        const int j = f & 7, lane = (f >> 3) & 63, s = (f >> 9) & 3, t = f >> 11;
        const int n = t * 16 + (lane & 15);
        const int k = s * 32 + ((lane >> 4) << 3) + j;
        wt1[f] = (bf16_t)(w1[k * DW_ + n] * wdw[n]);
    }
    for (int f = id; f < 16384; f += stride) {          // w2, N=128
        const int j = f & 7, lane = (f >> 3) & 63, s = (f >> 9) & 3, t = f >> 11;
        const int n = t * 16 + (lane & 15);
        const int k = s * 32 + ((lane >> 4) << 3) + j;
        wt2[f] = (bf16_t)(w2[k * C_ + n]);
    }
    for (int f = id; f < 32768; f += stride) {          // wf1, N=256
        const int j = f & 7, lane = (f >> 3) & 63, s = (f >> 9) & 3, t = f >> 11;
        const int n = t * 16 + (lane & 15);
        const int k = s * 32 + ((lane >> 4) << 3) + j;
        wtf1[f] = (bf16_t)(wf1[k * DW_ + n]);
    }
    for (int f = id; f < 16384; f += stride) {          // wf2, N=128
        const int j = f & 7, lane = (f >> 3) & 63, s = (f >> 9) & 3, t = f >> 11;
        const int n = t * 16 + (lane & 15);
        const int k = s * 32 + ((lane >> 4) << 3) + j;
        wtf2[f] = (bf16_t)(wf2[k * C_ + n]);
    }
}

// ---------------------------------------------------------------------------
// Phase 1: LN1 -> (w1*wdw) MFMA -> gate -> sg (bf16 if SGBF, else fp32) +
// gap partials.  64 pixels/block, 4 waves x 16 pixels.  One atomic/channel/
// block at kernel end (fire-and-forget; nothing waits on it).
// ---------------------------------------------------------------------------
template<int SGBF>
__global__ __launch_bounds__(256) void k_phase1(
    const float* __restrict__ x,
    const float* __restrict__ ln1s, const float* __restrict__ ln1b,
    const bf16_t* __restrict__ wt1, const float* __restrict__ b1f,
    float* __restrict__ sg_f, bf16_t* __restrict__ sg_h,
    float* __restrict__ gap)
{
    __shared__ __align__(16) bf16_t sA[64 * PA_];
    __shared__ float sRed[4 * C_];           // per-wave gap partials (2 KB)
    const int tid = threadIdx.x;
    const int pix0 = blockIdx.x * 64;
    const int batch = pix0 / HW_;

    // ---- LN1: 4 threads per pixel, 32 ch each ----
    {
        const int p = tid >> 2, sub = tid & 3;
        const float* xr = x + (size_t)(pix0 + p) * C_ + sub * 32;
        float4 v[8];
        float s = 0.f, ss = 0.f;
        #pragma unroll
        for (int u = 0; u < 8; u++) {
            v[u] = ld4(xr + u * 4);
            s  += v[u].x + v[u].y + v[u].z + v[u].w;
            ss += v[u].x * v[u].x + v[u].y * v[u].y + v[u].z * v[u].z + v[u].w * v[u].w;
        }
        s += __shfl_xor(s, 1); ss += __shfl_xor(ss, 1);
        s += __shfl_xor(s, 2); ss += __shfl_xor(ss, 2);
        const float mu  = s * (1.f / C_);
        const float var = ss * (1.f / C_) - mu * mu;
        const float rr  = rsqrtf(var + EPS_);
        #pragma unroll
        for (int u = 0; u < 8; u++) {
            const int c0 = sub * 32 + u * 4;
            const float4 sc = ld4(ln1s + c0), bi = ld4(ln1b + c0);
            bf16x4 o;
            o[0] = (bf16_t)((v[u].x - mu) * rr * sc.x + bi.x);
            o[1] = (bf16_t)((v[u].y - mu) * rr * sc.y + bi.y);
            o[2] = (bf16_t)((v[u].z - mu) * rr * sc.z + bi.z);
            o[3] = (bf16_t)((v[u].w - mu) * rr * sc.w + bi.w);
            *(bf16x4*)(&sA[p * PA_ + c0]) = o;
        }
    }
    __syncthreads();

    const int lane = tid & 63, wave = tid >> 6;
    const int l15 = lane & 15, quad = lane >> 4;

    bf16x8 af[4];
    #pragma unroll
    for (int s = 0; s < 4; s++)
        af[s] = *(const bf16x8*)(&sA[(wave * 16 + l15) * PA_ + s * 32 + quad * 8]);

    float gacc[8];
    #pragma unroll
    for (int t = 0; t < 8; t++) {
        f32x4 a0 = {0.f, 0.f, 0.f, 0.f};
        f32x4 a1 = {0.f, 0.f, 0.f, 0.f};
        #pragma unroll
        for (int s = 0; s < 4; s++) {
            const bf16x8 b0 = *(const bf16x8*)(wt1 + ((size_t)((t    ) * 4 + s) * 64 + lane) * 8);
            const bf16x8 b1 = *(const bf16x8*)(wt1 + ((size_t)((t + 8) * 4 + s) * 64 + lane) * 8);
            a0 = __builtin_amdgcn_mfma_f32_16x16x32_bf16(af[s], b0, a0, 0, 0, 0);
            a1 = __builtin_amdgcn_mfma_f32_16x16x32_bf16(af[s], b1, a1, 0, 0, 0);
        }
        const float bb0 = b1f[t * 16 + l15], bb1 = b1f[128 + t * 16 + l15];
        float gs = 0.f;
        #pragma unroll
        for (int r = 0; r < 4; r++) {
            const float g = (a0[r] + bb0) * (a1[r] + bb1);
            const size_t idx = (size_t)(pix0 + wave * 16 + quad * 4 + r) * C_ + t * 16 + l15;
            if constexpr (SGBF) sg_h[idx] = (bf16_t)g;
            else                sg_f[idx] = g;
            gs += g;            // fp32, pre-rounding (closer to reference)
        }
        gacc[t] = gs;           // stays in registers; NO atomic in the loop
    }

    // ---- gap reduction: butterfly over quads, LDS over waves, 1 atomic/ch ----
    #pragma unroll
    for (int t = 0; t < 8; t++) {
        float g = gacc[t];
        g += __shfl_xor(g, 16);
        g += __shfl_xor(g, 32);
        if (lane < 16) sRed[wave * C_ + t * 16 + lane] = g;
    }
    __syncthreads();
    if (tid < C_) {
        const float s4 = sRed[tid] + sRed[C_ + tid] + sRed[2 * C_ + tid] + sRed[3 * C_ + tid];
        atomicAdd(&gap[batch * C_ + tid], s4);
    }
}

// ---------------------------------------------------------------------------
// SE dense: att[b][d] = (gap[b]/HW) . wse[:,d] + bse[d]
// ---------------------------------------------------------------------------
__global__ __launch_bounds__(128) void k_se(
    const float* __restrict__ gap, const float* __restrict__ wse,
    const float* __restrict__ bse, float* __restrict__ att)
{
    const int b = blockIdx.x;
    const int d = threadIdx.x;
    float acc = bse[d];
    const float inv = 1.0f / (float)HW_;
    for (int cc = 0; cc < C_; cc++)
        acc = fmaf(gap[b * C_ + cc] * inv, wse[cc * C_ + d], acc);
    att[b * C_ + d] = acc;
}

// ---------------------------------------------------------------------------
// Phase 2 (round-1 structure, measured 193 us): sm=sg*att -> w2 MFMA -> y ->
// LN2 via ybuf LDS re-partition -> wf1 MFMA + gate -> wf2 MFMA -> out.
// 64 pixels/block.  sg read as bf16 when SGBF (halves its fetch traffic).
// NOTE (R2 post-mortem): do NOT replace the ybuf LN2 with in-register quad
// shuffles — the lockstep DS-chain between barriers cost +70 us despite
// higher occupancy.  Stage critical path >> wave-slot occupancy here.
// ---------------------------------------------------------------------------
template<int SGBF>
__global__ __launch_bounds__(256) void k_phase2(
    const float* __restrict__ x, const float* __restrict__ att,
    const bf16_t* __restrict__ wt2, const float* __restrict__ b2,
    const float* __restrict__ ln2s, const float* __restrict__ ln2b,
    const bf16_t* __restrict__ wtf1, const float* __restrict__ bf1,
    const bf16_t* __restrict__ wtf2, const float* __restrict__ bf2,
    const float* __restrict__ beta, const float* __restrict__ gamma,
    const float* __restrict__ sg_f, const bf16_t* __restrict__ sg_h,
    float* __restrict__ out)
{
    __shared__ __align__(16) bf16_t sA[64 * PA_];          // sm, then cn
    __shared__ __align__(16) float  ybuf[64 * 132];        // y fp32; later cg bf16
    bf16_t* cgb = (bf16_t*)ybuf;

    const int tid = threadIdx.x;
    const int pix0 = blockIdx.x * 64;
    const int batch = pix0 / HW_;

    // ---- sm = sg * att -> sA (bf16) ----
    {
        const int p = tid >> 2, sub = tid & 3;
        const float* ar = att + batch * C_ + sub * 32;
        if constexpr (SGBF) {
            const bf16_t* gr = sg_h + (size_t)(pix0 + p) * C_ + sub * 32;
            #pragma unroll
            for (int u = 0; u < 4; u++) {
                const bf16x8 g = *(const bf16x8*)(gr + u * 8);
                const float4 a0 = ld4(ar + u * 8), a1 = ld4(ar + u * 8 + 4);
                bf16x8 o;
                o[0] = (bf16_t)((float)g[0] * a0.x);
                o[1] = (bf16_t)((float)g[1] * a0.y);
                o[2] = (bf16_t)((float)g[2] * a0.z);
                o[3] = (bf16_t)((float)g[3] * a0.w);
                o[4] = (bf16_t)((float)g[4] * a1.x);
                o[5] = (bf16_t)((float)g[5] * a1.y);
                o[6] = (bf16_t)((float)g[6] * a1.z);
                o[7] = (bf16_t)((float)g[7] * a1.w);
                *(bf16x8*)(&sA[p * PA_ + sub * 32 + u * 8]) = o;
            }
        } else {
            const float* gr = sg_f + (size_t)(pix0 + p) * C_ + sub * 32;
            #pragma unroll
            for (int u = 0; u < 8; u++) {
                const float4 g = ld4(gr + u * 4), a = ld4(ar + u * 4);
                bf16x4 o;
                o[0] = (bf16_t)(g.x * a.x);
                o[1] = (bf16_t)(g.y * a.y);
                o[2] = (bf16_t)(g.z * a.z);
                o[3] = (bf16_t)(g.w * a.w);
                *(bf16x4*)(&sA[p * PA_ + sub * 32 + u * 4]) = o;
            }
        }
    }
    __syncthreads();

    const int lane = tid & 63, wave = tid >> 6;
    const int l15 = lane & 15, quad = lane >> 4;
    float yreg[32];

    // ---- w2 GEMM + residual -> yreg + ybuf ----
    {
        bf16x8 af[4];
        #pragma unroll
        for (int s = 0; s < 4; s++)
            af[s] = *(const bf16x8*)(&sA[(wave * 16 + l15) * PA_ + s * 32 + quad * 8]);
        #pragma unroll
        for (int t = 0; t < 8; t++) {
            f32x4 acc = {0.f, 0.f, 0.f, 0.f};
            #pragma unroll
            for (int s = 0; s < 4; s++) {
                const bf16x8 b = *(const bf16x8*)(wt2 + ((size_t)(t * 4 + s) * 64 + lane) * 8);
                acc = __builtin_amdgcn_mfma_f32_16x16x32_bf16(af[s], b, acc, 0, 0, 0);
            }
            const int n = t * 16 + l15;
            const float b2n = b2[n], bta = beta[n];
            #pragma unroll
            for (int r = 0; r < 4; r++) {
                const int m = wave * 16 + quad * 4 + r;
                const float xv = x[(size_t)(pix0 + m) * C_ + n];
                const float yv = xv + bta * (acc[r] + b2n);
                yreg[t * 4 + r] = yv;
                ybuf[m * 132 + n] = yv;
            }
        }
    }
    __syncthreads();

    // ---- LN2: ybuf -> sA (cn bf16) ----
    {
        const int p = tid >> 2, sub = tid & 3;
        float4 v[8];
        float s = 0.f, ss = 0.f;
        #pragma unroll
        for (int u = 0; u < 8; u++) {
            v[u] = *(const float4*)(&ybuf[p * 132 + sub * 32 + u * 4]);
            s  += v[u].x + v[u].y + v[u].z + v[u].w;
            ss += v[u].x * v[u].x + v[u].y * v[u].y + v[u].z * v[u].z + v[u].w * v[u].w;
        }
        s += __shfl_xor(s, 1); ss += __shfl_xor(ss, 1);
        s += __shfl_xor(s, 2); ss += __shfl_xor(ss, 2);
        const float mu  = s * (1.f / C_);
        const float var = ss * (1.f / C_) - mu * mu;
        const float rr  = rsqrtf(var + EPS_);
        #pragma unroll
        for (int u = 0; u < 8; u++) {
            const int c0 = sub * 32 + u * 4;
            const float4 sc = ld4(ln2s + c0), bi = ld4(ln2b + c0);
            bf16x4 o;
            o[0] = (bf16_t)((v[u].x - mu) * rr * sc.x + bi.x);
            o[1] = (bf16_t)((v[u].y - mu) * rr * sc.y + bi.y);
            o[2] = (bf16_t)((v[u].z - mu) * rr * sc.z + bi.z);
            o[3] = (bf16_t)((v[u].w - mu) * rr * sc.w + bi.w);
            *(bf16x4*)(&sA[p * PA_ + c0]) = o;
        }
    }
    __syncthreads();   // cn ready; ybuf dead -> reusable as cgb

    // ---- wf1 GEMM + gate -> cgb (bf16) ----
    {
        bf16x8 af[4];
        #pragma unroll
        for (int s = 0; s < 4; s++)
            af[s] = *(const bf16x8*)(&sA[(wave * 16 + l15) * PA_ + s * 32 + quad * 8]);
        #pragma unroll
        for (int t = 0; t < 8; t++) {
            f32x4 a0 = {0.f, 0.f, 0.f, 0.f};
            f32x4 a1 = {0.f, 0.f, 0.f, 0.f};
            #pragma unroll
            for (int s = 0; s < 4; s++) {
                const bf16x8 b0 = *(const bf16x8*)(wtf1 + ((size_t)((t    ) * 4 + s) * 64 + lane) * 8);
                const bf16x8 b1 = *(const bf16x8*)(wtf1 + ((size_t)((t + 8) * 4 + s) * 64 + lane) * 8);
                a0 = __builtin_amdgcn_mfma_f32_16x16x32_bf16(af[s], b0, a0, 0, 0, 0);
                a1 = __builtin_amdgcn_mfma_f32_16x16x32_bf16(af[s], b1, a1, 0, 0, 0);
            }
            const float f1a = bf1[t * 16 + l15], f1b = bf1[128 + t * 16 + l15];
            #pragma unroll
            for (int r = 0; r < 4; r++) {
                const float cg = (a0[r] + f1a) * (a1[r] + f1b);
                cgb[(wave * 16 + quad * 4 + r) * PA_ + t * 16 + l15] = (bf16_t)cg;
            }
        }
    }
    __syncthreads();

    // ---- wf2 GEMM + final residual -> out ----
    {
        bf16x8 af[4];
        #pragma unroll
        for (int s = 0; s < 4; s++)
            af[s] = *(const bf16x8*)(&cgb[(wave * 16 + l15) * PA_ + s * 32 + quad * 8]);
        #pragma unroll
        for (int t = 0; t < 8; t++) {
            f32x4 acc = {0.f, 0.f, 0.f, 0.f};
            #pragma unroll
            for (int s = 0; s < 4; s++) {
                const bf16x8 b = *(const bf16x8*)(wtf2 + ((size_t)(t * 4 + s) * 64 + lane) * 8);
                acc = __builtin_amdgcn_mfma_f32_16x16x32_bf16(af[s], b, acc, 0, 0, 0);
            }
            const int n = t * 16 + l15;
            const float fb = bf2[n], gm = gamma[n];
            #pragma unroll
            for (int r = 0; r < 4; r++) {
                const int m = wave * 16 + quad * 4 + r;
                out[(size_t)(pix0 + m) * C_ + n] = yreg[t * 4 + r] + gm * (acc[r] + fb);
            }
        }
    }
}

extern "C" void kernel_launch(void* const* d_in, const int* in_sizes, int n_in,
                              void* d_out, int out_size, void* d_ws, size_t ws_size,
                              hipStream_t stream)
{
    const float* x     = (const float*)d_in[0];
    const float* ln1s  = (const float*)d_in[1];
    const float* ln1b  = (const float*)d_in[2];
    const float* w1    = (const float*)d_in[3];
    const float* b1    = (const float*)d_in[4];
    const float* wdw   = (const float*)d_in[5];
    const float* bdw   = (const float*)d_in[6];
    const float* wse   = (const float*)d_in[7];
    const float* bse   = (const float*)d_in[8];
    const float* w2    = (const float*)d_in[9];
    const float* b2    = (const float*)d_in[10];
    const float* ln2s  = (const float*)d_in[11];
    const float* ln2b  = (const float*)d_in[12];
    const float* wf1   = (const float*)d_in[13];
    const float* bf1   = (const float*)d_in[14];
    const float* wf2   = (const float*)d_in[15];
    const float* bf2   = (const float*)d_in[16];
    const float* beta  = (const float*)d_in[17];
    const float* gamma = (const float*)d_in[18];

    float* out = (float*)d_out;
    char*  ws  = (char*)d_ws;
    float*  gap  = (float*)(ws);                 // 1024 f = 4 KB
    float*  attb = (float*)(ws + 4096);          // 1024 f = 4 KB
    float*  b1f  = (float*)(ws + 8192);          // 256 f  = 1 KB
    bf16_t* wt1  = (bf16_t*)(ws + 12288);        // 64 KB
    bf16_t* wt2  = (bf16_t*)(ws + 77824);        // 32 KB
    bf16_t* wtf1 = (bf16_t*)(ws + 110592);       // 64 KB
    bf16_t* wtf2 = (bf16_t*)(ws + 176128);       // 32 KB

    // bf16 sg intermediate lives at ws+1MB if the workspace is big enough;
    // otherwise fall back to fp32 sg staged in the output buffer (round-1 path).
    const size_t SG_OFF   = (size_t)1 << 20;
    const size_t SG_BYTES = (size_t)NPIX_ * C_ * sizeof(bf16_t);   // ~75.5 MB
    const bool   use_bf   = (ws_size >= SG_OFF + SG_BYTES);
    bf16_t* sgh = (bf16_t*)(ws + SG_OFF);

    k_prep<<<192, 256, 0, stream>>>(w1, b1, wdw, bdw, w2, wf1, wf2,
                                    wt1, wt2, wtf1, wtf2, b1f, gap);
    if (use_bf) {
        k_phase1<1><<<NPIX_ / 64, 256, 0, stream>>>(x, ln1s, ln1b, wt1, b1f,
                                                    out, sgh, gap);
        k_se<<<B_, C_, 0, stream>>>(gap, wse, bse, attb);
        k_phase2<1><<<NPIX_ / 64, 256, 0, stream>>>(x, attb, wt2, b2, ln2s, ln2b,
                                                    wtf1, bf1, wtf2, bf2, beta, gamma,
                                                    out, sgh, out);
    } else {
        k_phase1<0><<<NPIX_ / 64, 256, 0, stream>>>(x, ln1s, ln1b, wt1, b1f,
                                                    out, sgh, gap);
        k_se<<<B_, C_, 0, stream>>>(gap, wse, bse, attb);
        k_phase2<0><<<NPIX_ / 64, 256, 0, stream>>>(x, attb, wt2, b2, ln2s, ln2b,
                                                    wtf1, bf1, wtf2, bf2, beta, gamma,
                                                    out, sgh, out);
    }
}

// Round 4
// 451.480 us; speedup vs baseline: 1.3298x; 1.1319x over previous
//
#include <hip/hip_runtime.h>
#include <cstddef>

#define C_    128
#define DW_   256
#define HW_   (192 * 192)
#define B_    8
#define NPIX_ (B_ * HW_)
#define EPS_  1e-6f
#define PA_   136            // padded A-tile row stride in bf16 elems (272 B)

typedef __bf16 bf16_t;
typedef __bf16 bf16x8 __attribute__((ext_vector_type(8)));
typedef __bf16 bf16x4 __attribute__((ext_vector_type(4)));
typedef float  f32x4  __attribute__((ext_vector_type(4)));

__device__ __forceinline__ float4 ld4(const float* p) { return *(const float4*)p; }

// ---------------------------------------------------------------------------
// Prep: zero gap; fold depthwise affine into w1/b1; cast weights to bf16 in
// B-fragment order: flat[((t*4+s)*64+lane)*8 + j] = W[k][n], n = t*16+(lane&15),
// k = s*32 + (lane>>4)*8 + j.  (A/B fragment k-decomposition of 16x16x32.)
// ---------------------------------------------------------------------------
__global__ void k_prep(const float* __restrict__ w1, const float* __restrict__ b1,
                       const float* __restrict__ wdw, const float* __restrict__ bdw,
                       const float* __restrict__ w2, const float* __restrict__ wf1,
                       const float* __restrict__ wf2,
                       bf16_t* __restrict__ wt1, bf16_t* __restrict__ wt2,
                       bf16_t* __restrict__ wtf1, bf16_t* __restrict__ wtf2,
                       float* __restrict__ b1f, float* __restrict__ gap)
{
    const int id = blockIdx.x * blockDim.x + threadIdx.x;
    const int stride = gridDim.x * blockDim.x;
    for (int n = id; n < B_ * C_; n += stride)
        gap[n] = 0.f;                                   // replaces hipMemsetAsync
    for (int n = id; n < DW_; n += stride)
        b1f[n] = b1[n] * wdw[n] + bdw[n];
    for (int f = id; f < 32768; f += stride) {          // w1 (fold wdw), N=256
        const int j = f & 7, lane = (f >> 3) & 63, s = (f >> 9) & 3, t = f >> 11;
        const int n = t * 16 + (lane & 15);
        const int k = s * 32 + ((lane >> 4) << 3) + j;
        wt1[f] = (bf16_t)(w1[k * DW_ + n] * wdw[n]);
    }
    for (int f = id; f < 16384; f += stride) {          // w2, N=128
        const int j = f & 7, lane = (f >> 3) & 63, s = (f >> 9) & 3, t = f >> 11;
        const int n = t * 16 + (lane & 15);
        const int k = s * 32 + ((lane >> 4) << 3) + j;
        wt2[f] = (bf16_t)(w2[k * C_ + n]);
    }
    for (int f = id; f < 32768; f += stride) {          // wf1, N=256
        const int j = f & 7, lane = (f >> 3) & 63, s = (f >> 9) & 3, t = f >> 11;
        const int n = t * 16 + (lane & 15);
        const int k = s * 32 + ((lane >> 4) << 3) + j;
        wtf1[f] = (bf16_t)(wf1[k * DW_ + n]);
    }
    for (int f = id; f < 16384; f += stride) {          // wf2, N=128
        const int j = f & 7, lane = (f >> 3) & 63, s = (f >> 9) & 3, t = f >> 11;
        const int n = t * 16 + (lane & 15);
        const int k = s * 32 + ((lane >> 4) << 3) + j;
        wtf2[f] = (bf16_t)(wf2[k * C_ + n]);
    }
}

// ---------------------------------------------------------------------------
// Phase 1: LN1 -> (w1*wdw) MFMA -> gate -> sg (bf16 if SGBF) + gap partials.
// CHANNEL-SLICE ownership: wave w owns t in {2w, 2w+1} (32 of 256 hidden
// channels incl. the n/n+128 gate pair) for ALL 64 block pixels.  B-fragments
// live in registers (8 b128 loads per t vs 64 per wave before); A-fragments
// re-read from LDS per (t,m).  gap: single-writer per channel -> no cross-
// wave sum.  One atomic/channel/block at kernel end (fire-and-forget).
// ---------------------------------------------------------------------------
template<int SGBF>
__global__ __launch_bounds__(256) void k_phase1(
    const float* __restrict__ x,
    const float* __restrict__ ln1s, const float* __restrict__ ln1b,
    const bf16_t* __restrict__ wt1, const float* __restrict__ b1f,
    float* __restrict__ sg_f, bf16_t* __restrict__ sg_h,
    float* __restrict__ gap)
{
    __shared__ __align__(16) bf16_t sA[64 * PA_];
    __shared__ float sRed[C_];               // gap partials, single writer per ch
    const int tid = threadIdx.x;
    const int pix0 = blockIdx.x * 64;
    const int batch = pix0 / HW_;

    // ---- LN1: 4 threads per pixel, 32 ch each ----
    {
        const int p = tid >> 2, sub = tid & 3;
        const float* xr = x + (size_t)(pix0 + p) * C_ + sub * 32;
        float4 v[8];
        float s = 0.f, ss = 0.f;
        #pragma unroll
        for (int u = 0; u < 8; u++) {
            v[u] = ld4(xr + u * 4);
            s  += v[u].x + v[u].y + v[u].z + v[u].w;
            ss += v[u].x * v[u].x + v[u].y * v[u].y + v[u].z * v[u].z + v[u].w * v[u].w;
        }
        s += __shfl_xor(s, 1); ss += __shfl_xor(ss, 1);
        s += __shfl_xor(s, 2); ss += __shfl_xor(ss, 2);
        const float mu  = s * (1.f / C_);
        const float var = ss * (1.f / C_) - mu * mu;
        const float rr  = rsqrtf(var + EPS_);
        #pragma unroll
        for (int u = 0; u < 8; u++) {
            const int c0 = sub * 32 + u * 4;
            const float4 sc = ld4(ln1s + c0), bi = ld4(ln1b + c0);
            bf16x4 o;
            o[0] = (bf16_t)((v[u].x - mu) * rr * sc.x + bi.x);
            o[1] = (bf16_t)((v[u].y - mu) * rr * sc.y + bi.y);
            o[2] = (bf16_t)((v[u].z - mu) * rr * sc.z + bi.z);
            o[3] = (bf16_t)((v[u].w - mu) * rr * sc.w + bi.w);
            *(bf16x4*)(&sA[p * PA_ + c0]) = o;
        }
    }
    __syncthreads();

    const int lane = tid & 63, wave = tid >> 6;
    const int l15 = lane & 15, quad = lane >> 4;

    #pragma unroll
    for (int tt = 0; tt < 2; tt++) {
        const int t = wave * 2 + tt;
        bf16x8 b0[4], b1[4];                 // this wave's weight slice, in regs
        #pragma unroll
        for (int s = 0; s < 4; s++) {
            b0[s] = *(const bf16x8*)(wt1 + ((size_t)((t    ) * 4 + s) * 64 + lane) * 8);
            b1[s] = *(const bf16x8*)(wt1 + ((size_t)((t + 8) * 4 + s) * 64 + lane) * 8);
        }
        const float bb0 = b1f[t * 16 + l15], bb1 = b1f[128 + t * 16 + l15];
        float gs = 0.f;
        #pragma unroll
        for (int m = 0; m < 4; m++) {        // all 4 pixel M-tiles of the block
            bf16x8 af[4];
            #pragma unroll
            for (int s = 0; s < 4; s++)
                af[s] = *(const bf16x8*)(&sA[(m * 16 + l15) * PA_ + s * 32 + quad * 8]);
            f32x4 a0 = {0.f, 0.f, 0.f, 0.f};
            f32x4 a1 = {0.f, 0.f, 0.f, 0.f};
            #pragma unroll
            for (int s = 0; s < 4; s++) {
                a0 = __builtin_amdgcn_mfma_f32_16x16x32_bf16(af[s], b0[s], a0, 0, 0, 0);
                a1 = __builtin_amdgcn_mfma_f32_16x16x32_bf16(af[s], b1[s], a1, 0, 0, 0);
            }
            #pragma unroll
            for (int r = 0; r < 4; r++) {
                const float g = (a0[r] + bb0) * (a1[r] + bb1);
                const size_t idx = (size_t)(pix0 + m * 16 + quad * 4 + r) * C_ + t * 16 + l15;
                if constexpr (SGBF) sg_h[idx] = (bf16_t)g;
                else                sg_f[idx] = g;
                gs += g;                     // in-lane partial over 16 pixels
            }
        }
        gs += __shfl_xor(gs, 16);            // sum over quads -> all 64 pixels
        gs += __shfl_xor(gs, 32);
        if (lane < 16) sRed[t * 16 + lane] = gs;   // unique writer per channel
    }
    __syncthreads();
    if (tid < C_)
        atomicAdd(&gap[batch * C_ + tid], sRed[tid]);
}

// ---------------------------------------------------------------------------
// SE dense: att[b][d] = (gap[b]/HW) . wse[:,d] + bse[d]
// ---------------------------------------------------------------------------
__global__ __launch_bounds__(128) void k_se(
    const float* __restrict__ gap, const float* __restrict__ wse,
    const float* __restrict__ bse, float* __restrict__ att)
{
    const int b = blockIdx.x;
    const int d = threadIdx.x;
    float acc = bse[d];
    const float inv = 1.0f / (float)HW_;
    for (int cc = 0; cc < C_; cc++)
        acc = fmaf(gap[b * C_ + cc] * inv, wse[cc * C_ + d], acc);
    att[b * C_ + d] = acc;
}

// ---------------------------------------------------------------------------
// Phase 2: sm=sg*att -> w2 MFMA -> y -> LN2 via ybuf -> wf1 MFMA + gate ->
// wf2 MFMA -> out.  CHANNEL-SLICE wave ownership (see phase 1): per-wave
// weight loads 128 -> 32 b128, held in registers across the pixel m-loop.
// x residual values prefetched at kernel top (issue-early; consumed from
// registers inside the w2 stage instead of fresh HBM loads).
// NOTE (R2 post-mortem): keep the ybuf LDS re-partition LN2 — in-register
// quad-shuffle LN2 cost +70 us (lockstep DS-chain).
// ---------------------------------------------------------------------------
template<int SGBF>
__global__ __launch_bounds__(256) void k_phase2(
    const float* __restrict__ x, const float* __restrict__ att,
    const bf16_t* __restrict__ wt2, const float* __restrict__ b2,
    const float* __restrict__ ln2s, const float* __restrict__ ln2b,
    const bf16_t* __restrict__ wtf1, const float* __restrict__ bf1,
    const bf16_t* __restrict__ wtf2, const float* __restrict__ bf2,
    const float* __restrict__ beta, const float* __restrict__ gamma,
    const float* __restrict__ sg_f, const bf16_t* __restrict__ sg_h,
    float* __restrict__ out)
{
    __shared__ __align__(16) bf16_t sA[64 * PA_];          // sm, then cn
    __shared__ __align__(16) float  ybuf[64 * 132];        // y fp32; later cg bf16
    bf16_t* cgb = (bf16_t*)ybuf;

    const int tid = threadIdx.x;
    const int pix0 = blockIdx.x * 64;
    const int batch = pix0 / HW_;
    const int lane = tid & 63, wave = tid >> 6;
    const int l15 = lane & 15, quad = lane >> 4;

    // ---- x residual prefetch (issue-early; latency hides under sm staging) --
    float xr[2][4][4];
    #pragma unroll
    for (int tt = 0; tt < 2; tt++)
        #pragma unroll
        for (int m = 0; m < 4; m++)
            #pragma unroll
            for (int r = 0; r < 4; r++)
                xr[tt][m][r] = x[(size_t)(pix0 + m * 16 + quad * 4 + r) * C_
                                 + (wave * 2 + tt) * 16 + l15];

    // ---- sm = sg * att -> sA (bf16) ----
    {
        const int p = tid >> 2, sub = tid & 3;
        const float* ar = att + batch * C_ + sub * 32;
        if constexpr (SGBF) {
            const bf16_t* gr = sg_h + (size_t)(pix0 + p) * C_ + sub * 32;
            #pragma unroll
            for (int u = 0; u < 4; u++) {
                const bf16x8 g = *(const bf16x8*)(gr + u * 8);
                const float4 a0 = ld4(ar + u * 8), a1 = ld4(ar + u * 8 + 4);
                bf16x8 o;
                o[0] = (bf16_t)((float)g[0] * a0.x);
                o[1] = (bf16_t)((float)g[1] * a0.y);
                o[2] = (bf16_t)((float)g[2] * a0.z);
                o[3] = (bf16_t)((float)g[3] * a0.w);
                o[4] = (bf16_t)((float)g[4] * a1.x);
                o[5] = (bf16_t)((float)g[5] * a1.y);
                o[6] = (bf16_t)((float)g[6] * a1.z);
                o[7] = (bf16_t)((float)g[7] * a1.w);
                *(bf16x8*)(&sA[p * PA_ + sub * 32 + u * 8]) = o;
            }
        } else {
            const float* gr = sg_f + (size_t)(pix0 + p) * C_ + sub * 32;
            #pragma unroll
            for (int u = 0; u < 8; u++) {
                const float4 g = ld4(gr + u * 4), a = ld4(ar + u * 4);
                bf16x4 o;
                o[0] = (bf16_t)(g.x * a.x);
                o[1] = (bf16_t)(g.y * a.y);
                o[2] = (bf16_t)(g.z * a.z);
                o[3] = (bf16_t)(g.w * a.w);
                *(bf16x4*)(&sA[p * PA_ + sub * 32 + u * 4]) = o;
            }
        }
    }
    __syncthreads();

    float yreg[2][4][4];

    // ---- w2 GEMM + residual -> yreg + ybuf ----
    #pragma unroll
    for (int tt = 0; tt < 2; tt++) {
        const int t = wave * 2 + tt;
        bf16x8 bw[4];
        #pragma unroll
        for (int s = 0; s < 4; s++)
            bw[s] = *(const bf16x8*)(wt2 + ((size_t)(t * 4 + s) * 64 + lane) * 8);
        const int n = t * 16 + l15;
        const float b2n = b2[n], bta = beta[n];
        #pragma unroll
        for (int m = 0; m < 4; m++) {
            bf16x8 af[4];
            #pragma unroll
            for (int s = 0; s < 4; s++)
                af[s] = *(const bf16x8*)(&sA[(m * 16 + l15) * PA_ + s * 32 + quad * 8]);
            f32x4 acc = {0.f, 0.f, 0.f, 0.f};
            #pragma unroll
            for (int s = 0; s < 4; s++)
                acc = __builtin_amdgcn_mfma_f32_16x16x32_bf16(af[s], bw[s], acc, 0, 0, 0);
            #pragma unroll
            for (int r = 0; r < 4; r++) {
                const float yv = xr[tt][m][r] + bta * (acc[r] + b2n);
                yreg[tt][m][r] = yv;
                ybuf[(m * 16 + quad * 4 + r) * 132 + n] = yv;
            }
        }
    }
    __syncthreads();

    // ---- LN2: ybuf -> sA (cn bf16) ----
    {
        const int p = tid >> 2, sub = tid & 3;
        float4 v[8];
        float s = 0.f, ss = 0.f;
        #pragma unroll
        for (int u = 0; u < 8; u++) {
            v[u] = *(const float4*)(&ybuf[p * 132 + sub * 32 + u * 4]);
            s  += v[u].x + v[u].y + v[u].z + v[u].w;
            ss += v[u].x * v[u].x + v[u].y * v[u].y + v[u].z * v[u].z + v[u].w * v[u].w;
        }
        s += __shfl_xor(s, 1); ss += __shfl_xor(ss, 1);
        s += __shfl_xor(s, 2); ss += __shfl_xor(ss, 2);
        const float mu  = s * (1.f / C_);
        const float var = ss * (1.f / C_) - mu * mu;
        const float rr  = rsqrtf(var + EPS_);
        #pragma unroll
        for (int u = 0; u < 8; u++) {
            const int c0 = sub * 32 + u * 4;
            const float4 sc = ld4(ln2s + c0), bi = ld4(ln2b + c0);
            bf16x4 o;
            o[0] = (bf16_t)((v[u].x - mu) * rr * sc.x + bi.x);
            o[1] = (bf16_t)((v[u].y - mu) * rr * sc.y + bi.y);
            o[2] = (bf16_t)((v[u].z - mu) * rr * sc.z + bi.z);
            o[3] = (bf16_t)((v[u].w - mu) * rr * sc.w + bi.w);
            *(bf16x4*)(&sA[p * PA_ + c0]) = o;
        }
    }
    __syncthreads();   // cn ready; ybuf dead -> reusable as cgb

    // ---- wf1 GEMM + gate -> cgb (bf16) ----
    #pragma unroll
    for (int tt = 0; tt < 2; tt++) {
        const int t = wave * 2 + tt;
        bf16x8 c0[4], c1[4];
        #pragma unroll
        for (int s = 0; s < 4; s++) {
            c0[s] = *(const bf16x8*)(wtf1 + ((size_t)((t    ) * 4 + s) * 64 + lane) * 8);
            c1[s] = *(const bf16x8*)(wtf1 + ((size_t)((t + 8) * 4 + s) * 64 + lane) * 8);
        }
        const float f1a = bf1[t * 16 + l15], f1b = bf1[128 + t * 16 + l15];
        #pragma unroll
        for (int m = 0; m < 4; m++) {
            bf16x8 af[4];
            #pragma unroll
            for (int s = 0; s < 4; s++)
                af[s] = *(const bf16x8*)(&sA[(m * 16 + l15) * PA_ + s * 32 + quad * 8]);
            f32x4 a0 = {0.f, 0.f, 0.f, 0.f};
            f32x4 a1 = {0.f, 0.f, 0.f, 0.f};
            #pragma unroll
            for (int s = 0; s < 4; s++) {
                a0 = __builtin_amdgcn_mfma_f32_16x16x32_bf16(af[s], c0[s], a0, 0, 0, 0);
                a1 = __builtin_amdgcn_mfma_f32_16x16x32_bf16(af[s], c1[s], a1, 0, 0, 0);
            }
            #pragma unroll
            for (int r = 0; r < 4; r++) {
                const float cg = (a0[r] + f1a) * (a1[r] + f1b);
                cgb[(m * 16 + quad * 4 + r) * PA_ + t * 16 + l15] = (bf16_t)cg;
            }
        }
    }
    __syncthreads();

    // ---- wf2 GEMM + final residual -> out ----
    #pragma unroll
    for (int tt = 0; tt < 2; tt++) {
        const int t = wave * 2 + tt;
        bf16x8 bw[4];
        #pragma unroll
        for (int s = 0; s < 4; s++)
            bw[s] = *(const bf16x8*)(wtf2 + ((size_t)(t * 4 + s) * 64 + lane) * 8);
        const int n = t * 16 + l15;
        const float fb = bf2[n], gm = gamma[n];
        #pragma unroll
        for (int m = 0; m < 4; m++) {
            bf16x8 af[4];
            #pragma unroll
            for (int s = 0; s < 4; s++)
                af[s] = *(const bf16x8*)(&cgb[(m * 16 + l15) * PA_ + s * 32 + quad * 8]);
            f32x4 acc = {0.f, 0.f, 0.f, 0.f};
            #pragma unroll
            for (int s = 0; s < 4; s++)
                acc = __builtin_amdgcn_mfma_f32_16x16x32_bf16(af[s], bw[s], acc, 0, 0, 0);
            #pragma unroll
            for (int r = 0; r < 4; r++)
                out[(size_t)(pix0 + m * 16 + quad * 4 + r) * C_ + n] =
                    yreg[tt][m][r] + gm * (acc[r] + fb);
        }
    }
}

extern "C" void kernel_launch(void* const* d_in, const int* in_sizes, int n_in,
                              void* d_out, int out_size, void* d_ws, size_t ws_size,
                              hipStream_t stream)
{
    const float* x     = (const float*)d_in[0];
    const float* ln1s  = (const float*)d_in[1];
    const float* ln1b  = (const float*)d_in[2];
    const float* w1    = (const float*)d_in[3];
    const float* b1    = (const float*)d_in[4];
    const float* wdw   = (const float*)d_in[5];
    const float* bdw   = (const float*)d_in[6];
    const float* wse   = (const float*)d_in[7];
    const float* bse   = (const float*)d_in[8];
    const float* w2    = (const float*)d_in[9];
    const float* b2    = (const float*)d_in[10];
    const float* ln2s  = (const float*)d_in[11];
    const float* ln2b  = (const float*)d_in[12];
    const float* wf1   = (const float*)d_in[13];
    const float* bf1   = (const float*)d_in[14];
    const float* wf2   = (const float*)d_in[15];
    const float* bf2   = (const float*)d_in[16];
    const float* beta  = (const float*)d_in[17];
    const float* gamma = (const float*)d_in[18];

    float* out = (float*)d_out;
    char*  ws  = (char*)d_ws;
    float*  gap  = (float*)(ws);                 // 1024 f = 4 KB
    float*  attb = (float*)(ws + 4096);          // 1024 f = 4 KB
    float*  b1f  = (float*)(ws + 8192);          // 256 f  = 1 KB
    bf16_t* wt1  = (bf16_t*)(ws + 12288);        // 64 KB
    bf16_t* wt2  = (bf16_t*)(ws + 77824);        // 32 KB
    bf16_t* wtf1 = (bf16_t*)(ws + 110592);       // 64 KB
    bf16_t* wtf2 = (bf16_t*)(ws + 176128);       // 32 KB

    // bf16 sg intermediate lives at ws+1MB if the workspace is big enough;
    // otherwise fall back to fp32 sg staged in the output buffer.
    const size_t SG_OFF   = (size_t)1 << 20;
    const size_t SG_BYTES = (size_t)NPIX_ * C_ * sizeof(bf16_t);   // ~75.5 MB
    const bool   use_bf   = (ws_size >= SG_OFF + SG_BYTES);
    bf16_t* sgh = (bf16_t*)(ws + SG_OFF);

    k_prep<<<192, 256, 0, stream>>>(w1, b1, wdw, bdw, w2, wf1, wf2,
                                    wt1, wt2, wtf1, wtf2, b1f, gap);
    if (use_bf) {
        k_phase1<1><<<NPIX_ / 64, 256, 0, stream>>>(x, ln1s, ln1b, wt1, b1f,
                                                    out, sgh, gap);
        k_se<<<B_, C_, 0, stream>>>(gap, wse, bse, attb);
        k_phase2<1><<<NPIX_ / 64, 256, 0, stream>>>(x, attb, wt2, b2, ln2s, ln2b,
                                                    wtf1, bf1, wtf2, bf2, beta, gamma,
                                                    out, sgh, out);
    } else {
        k_phase1<0><<<NPIX_ / 64, 256, 0, stream>>>(x, ln1s, ln1b, wt1, b1f,
                                                    out, sgh, gap);
        k_se<<<B_, C_, 0, stream>>>(gap, wse, bse, attb);
        k_phase2<0><<<NPIX_ / 64, 256, 0, stream>>>(x, attb, wt2, b2, ln2s, ln2b,
                                                    wtf1, bf1, wtf2, bf2, beta, gamma,
                                                    out, sgh, out);
    }
}